// Round 4
// baseline (556.391 us; speedup 1.0000x reference)
//
#include <hip/hip_runtime.h>
#include <hip/hip_bf16.h>
#include <stdint.h>

#define BATCH 16384
#define MARK  1024
#define NF    40
#define FE    16
#define KDIM  2688      // 2*1024 + 40*16
#define HID   4096
#define BK    64
#define NKT   (KDIM / BK)   // 42 K-tiles, 21 iterations x 2

typedef __bf16 bf16x8 __attribute__((ext_vector_type(8)));
typedef float  f32x16 __attribute__((ext_vector_type(16)));

static __device__ __forceinline__ unsigned short f2bf(float f) {
  union { float f; uint32_t u; } v; v.f = f;
  uint32_t u = v.u;
  uint32_t r = (u + 0x7FFFu + ((u >> 16) & 1u)) >> 16;
  return (unsigned short)r;
}

__global__ __launch_bounds__(256) void build_concat(
    const float* __restrict__ emb_i, const float* __restrict__ emb_a,
    const int* __restrict__ mask, const float* __restrict__ fon,
    const float* __restrict__ foff, unsigned short* __restrict__ out) {
  const int b = blockIdx.x;
  const float4* ri = (const float4*)(emb_i + (size_t)b * MARK);
  const float4* ra = (const float4*)(emb_a + (size_t)b * MARK);
  const int* mrow = mask + b * NF;
  unsigned short* orow = out + (size_t)b * KDIM;
  for (int g = threadIdx.x; g < KDIM / 4; g += 256) {
    const int base = g * 4;
    float4 v;
    if (base < MARK) {
      v = ri[g];
    } else if (base < 2 * MARK) {
      v = ra[g - MARK / 4];
    } else {
      const int idx = base - 2 * MARK;
      const int f = idx >> 4;
      const float* tab = (mrow[f] > 0) ? fon : foff;
      v = *(const float4*)(tab + f * FE + (idx & 15));
    }
    ushort4 o;
    o.x = f2bf(v.x); o.y = f2bf(v.y); o.z = f2bf(v.z); o.w = f2bf(v.w);
    *(ushort4*)(orow + base) = o;
  }
}

__global__ __launch_bounds__(256) void convert_w1(
    const float* __restrict__ w, unsigned short* __restrict__ o, int n4) {
  const int stride = gridDim.x * 256;
  for (int i = blockIdx.x * 256 + threadIdx.x; i < n4; i += stride) {
    float4 v = ((const float4*)w)[i];
    ushort4 u;
    u.x = f2bf(v.x); u.y = f2bf(v.y); u.z = f2bf(v.z); u.w = f2bf(v.w);
    ((ushort4*)o)[i] = u;
  }
}

__global__ __launch_bounds__(256) void out_init(float* __restrict__ out,
                                                const float* __restrict__ b2) {
  const int i = blockIdx.x * 256 + threadIdx.x;
  if (i < BATCH) out[i] = b2[0];
}

#define GL16(g, l)                                                              \
  __builtin_amdgcn_global_load_lds(                                             \
      (const __attribute__((address_space(1))) void*)(g),                       \
      (__attribute__((address_space(3))) void*)(l), 16, 0, 0)

#define BAR()        __builtin_amdgcn_s_barrier()
#define WAIT_LGKM0() asm volatile("s_waitcnt lgkmcnt(0)" ::: "memory")
#define WAIT_VM6()   asm volatile("s_waitcnt vmcnt(6)" ::: "memory")

// 256x256 tile, BK=64, 8 waves (2M x 4N), 4-phase schedule, 32x32x16 MFMA.
// Phase = one 64-row half of the wave's 128x64 panel x full 64 cols
// (2x2 tiles x 4 ksteps = 16 MFMA). Counted vmcnt(6) at P2/P4.
// LDS XOR-swizzle at 16B-chunk granularity, applied on the global source
// address (global_load_lds writes linearly) and on the ds_read address.
__global__ __launch_bounds__(512, 2) void gemm_fused(
    const unsigned short* __restrict__ A,   // [BATCH, KDIM] bf16
    const unsigned short* __restrict__ Wb,  // [HID, KDIM]  bf16
    const float* __restrict__ b1,
    const float* __restrict__ w2,
    float* __restrict__ out) {
  __shared__ unsigned short sA[2][256 * BK];   // 64 KB
  __shared__ unsigned short sB[2][256 * BK];   // 64 KB
  __shared__ float spart[2][4][128];           // 4 KB cross-wave reduce

  const int tid  = threadIdx.x;
  const int wid  = tid >> 6;
  const int lane = tid & 63;
  const int l31  = lane & 31;   // MFMA fragment row (A) / col (B)
  const int hi   = lane >> 5;   // k-half selector
  const int wm   = wid >> 2;    // wave M index (0..1)
  const int wn   = wid & 3;     // wave N index (0..3)

  // ---- XCD rectangle swizzle (bijective over 1024 = 8 x 4 x 8 x 4)
  const int bid = blockIdx.x;
  const int xcd = bid & 7;
  const int j   = bid >> 3;
  const int sub = j >> 5;
  const int sm  = (j >> 2) & 7;
  const int sn  = j & 3;
  const int tile_m = (xcd >> 1) * 16 + (sub >> 1) * 8 + sm;   // 0..63
  const int tile_n = (xcd & 1) * 8 + (sub & 1) * 4 + sn;      // 0..15

  // staging: lane l writes LDS row r0+(l>>3), chunk (l&7); source chunk
  // pre-swizzled so stored chunk c of row r holds source chunk c^(r&7).
  const int lrow = lane >> 3;
  const int lsrc = ((lane & 7) ^ lrow) * 8;   // elements
  const unsigned short* Aptr =
      A + ((size_t)tile_m * 256 + lrow) * KDIM + lsrc;
  const unsigned short* Bptr =
      Wb + ((size_t)tile_n * 256 + lrow) * KDIM + lsrc;

  // read-side swizzled chunk offsets (elements) per kstep: row&7 == lane&7
  int cko[4];
#pragma unroll
  for (int k_ = 0; k_ < 4; ++k_)
    cko[k_] = (((2 * k_ + hi) ^ (lane & 7)) * 8);

// A unit U in {0,1}: rows U*128 + g*64 + wid*8, 2 gloads/thread
#define STAGEA(BUF, U, KT)                                                     \
  { _Pragma("unroll") for (int g_ = 0; g_ < 2; ++g_) {                         \
      const int r0 = (U)*128 + g_ * 64 + wid * 8;                              \
      GL16(Aptr + (size_t)r0 * KDIM + (size_t)(KT)*BK, &sA[BUF][r0 * BK]); } }

#define STAGEB(BUF, U, KT)                                                     \
  { _Pragma("unroll") for (int g_ = 0; g_ < 2; ++g_) {                         \
      const int r0 = (U)*128 + g_ * 64 + wid * 8;                              \
      GL16(Bptr + (size_t)r0 * KDIM + (size_t)(KT)*BK, &sB[BUF][r0 * BK]); } }

// af[mt][k]: A rows wm*128 + MH*64 + mt*32 + l31, k-chunk cko[k]
#define LOADA(BUF, MH)                                                         \
  { _Pragma("unroll") for (int mt_ = 0; mt_ < 2; ++mt_) {                      \
      const unsigned short* p =                                                \
          &sA[BUF][(wm * 128 + (MH)*64 + mt_ * 32 + l31) * BK];                \
      _Pragma("unroll") for (int k_ = 0; k_ < 4; ++k_)                         \
          af[mt_][k_] = *(const bf16x8*)(p + cko[k_]); } }

// bfr[nt][k]: B rows wn*64 + nt*32 + l31 (both 32-col tiles)
#define LOADB(BUF)                                                             \
  { _Pragma("unroll") for (int nt_ = 0; nt_ < 2; ++nt_) {                      \
      const unsigned short* p =                                                \
          &sB[BUF][(wn * 64 + nt_ * 32 + l31) * BK];                           \
      _Pragma("unroll") for (int k_ = 0; k_ < 4; ++k_)                         \
          bfr[nt_][k_] = *(const bf16x8*)(p + cko[k_]); } }

#define MMA(MH)                                                                \
  { __builtin_amdgcn_s_setprio(1);                                             \
    _Pragma("unroll") for (int k_ = 0; k_ < 4; ++k_)                           \
    _Pragma("unroll") for (int mt_ = 0; mt_ < 2; ++mt_)                        \
    _Pragma("unroll") for (int nt_ = 0; nt_ < 2; ++nt_)                        \
      acc[(MH)*2 + mt_][nt_] = __builtin_amdgcn_mfma_f32_32x32x16_bf16(        \
          af[mt_][k_], bfr[nt_][k_], acc[(MH)*2 + mt_][nt_], 0, 0, 0);         \
    __builtin_amdgcn_s_setprio(0); }

  f32x16 acc[4][2];
#pragma unroll
  for (int i = 0; i < 4; ++i)
#pragma unroll
    for (int n_ = 0; n_ < 2; ++n_)
#pragma unroll
      for (int r_ = 0; r_ < 16; ++r_) acc[i][n_][r_] = 0.f;
  bf16x8 af[2][4], bfr[2][4];

  // hoist epilogue params (tiny, L2-resident)
  float b1v[2], w2v[2];
#pragma unroll
  for (int nt_ = 0; nt_ < 2; ++nt_) {
    const int col = tile_n * 256 + wn * 64 + nt_ * 32 + l31;
    b1v[nt_] = b1[col];
    w2v[nt_] = w2[col];
  }

  // ---- prologue: buf0 <- kt0 (A0,B0,B1,A1 = 8 loads), buf1 <- kt1 (A0,B0,B1)
  STAGEA(0, 0, 0); STAGEB(0, 0, 0); STAGEB(0, 1, 0); STAGEA(0, 1, 0);
  STAGEA(1, 0, 1); STAGEB(1, 0, 1); STAGEB(1, 1, 1);
  WAIT_VM6();   // buf0's 8 landed; buf1's 6 in flight
  BAR();

#pragma unroll 1
  for (int t = 0; t < NKT; t += 2) {
    int t2 = t + 2; if (t2 >= NKT) t2 -= NKT;   // wrapped prefetch keeps
    int t3 = t + 3; if (t3 >= NKT) t3 -= NKT;   // vmcnt counts uniform
    // P1: MH0 of even tile (buf0); complete buf1 (A1 <- kt+1)
    LOADA(0, 0); LOADB(0);
    STAGEA(1, 1, t + 1);
    BAR(); WAIT_LGKM0();
    MMA(0);
    BAR();
    // P2: MH1 of even tile; stage buf0{A0,B0,B1} <- kt+2
    LOADA(0, 1);
    STAGEA(0, 0, t2); STAGEB(0, 0, t2); STAGEB(0, 1, t2);
    BAR(); WAIT_LGKM0();
    MMA(1);
    WAIT_VM6();                          // buf1 (kt+1) fully landed
    BAR();
    // P3: MH0 of odd tile (buf1); stage buf0{A1} <- kt+2
    LOADA(1, 0); LOADB(1);
    STAGEA(0, 1, t2);
    BAR(); WAIT_LGKM0();
    MMA(0);
    BAR();
    // P4: MH1 of odd tile; stage buf1{B0,B1,A0} <- kt+3
    LOADA(1, 1);
    STAGEB(1, 0, t3); STAGEB(1, 1, t3); STAGEA(1, 0, t3);
    BAR(); WAIT_LGKM0();
    MMA(1);
    WAIT_VM6();                          // buf0 (kt+2) fully landed
    BAR();
  }

  // ---- fused epilogue: out[row] += sum_cols relu(acc + b1[col]) * w2[col]
  // C/D layout (32x32): col = l31, row = (reg&3) + 8*(reg>>2) + 4*hi
#pragma unroll
  for (int mt4 = 0; mt4 < 4; ++mt4) {
#pragma unroll
    for (int r_ = 0; r_ < 16; ++r_) {
      float h0 = acc[mt4][0][r_] + b1v[0];
      float h1 = acc[mt4][1][r_] + b1v[1];
      h0 = h0 > 0.f ? h0 : 0.f;
      h1 = h1 > 0.f ? h1 : 0.f;
      float s = fmaf(h0, w2v[0], h1 * w2v[1]);
      s += __shfl_xor(s, 1, 32);
      s += __shfl_xor(s, 2, 32);
      s += __shfl_xor(s, 4, 32);
      s += __shfl_xor(s, 8, 32);
      s += __shfl_xor(s, 16, 32);
      if (l31 == 0)
        spart[wm][wn][mt4 * 32 + (r_ & 3) + 8 * (r_ >> 2) + 4 * hi] = s;
    }
  }
  __syncthreads();
  if (tid < 256) {
    const int rl = tid & 127, wmr = tid >> 7;
    float s = spart[wmr][0][rl] + spart[wmr][1][rl] +
              spart[wmr][2][rl] + spart[wmr][3][rl];
    atomicAdd(&out[(size_t)tile_m * 256 + tid], s);
  }
}

extern "C" void kernel_launch(void* const* d_in, const int* in_sizes, int n_in,
                              void* d_out, int out_size, void* d_ws, size_t ws_size,
                              hipStream_t stream) {
  const float* emb_i = (const float*)d_in[0];
  const float* emb_a = (const float*)d_in[1];
  const int*   fmask = (const int*)d_in[2];
  const float* fon   = (const float*)d_in[3];
  const float* foff  = (const float*)d_in[4];
  const float* W1    = (const float*)d_in[5];
  const float* b1    = (const float*)d_in[6];
  const float* W2    = (const float*)d_in[7];
  const float* b2    = (const float*)d_in[8];
  float* out = (float*)d_out;

  unsigned short* concat = (unsigned short*)d_ws;                 // BATCH*KDIM bf16
  unsigned short* w1b    = concat + (size_t)BATCH * KDIM;         // HID*KDIM bf16

  build_concat<<<BATCH, 256, 0, stream>>>(emb_i, emb_a, fmask, fon, foff, concat);
  convert_w1<<<2048, 256, 0, stream>>>(W1, w1b, HID * KDIM / 4);
  out_init<<<BATCH / 256, 256, 0, stream>>>(out, b2);
  gemm_fused<<<(BATCH / 256) * (HID / 256), 512, 0, stream>>>(concat, w1b, b1,
                                                              W2, out);
}